// Round 3
// baseline (180.896 us; speedup 1.0000x reference)
//
#include <hip/hip_runtime.h>
#include <hip/hip_cooperative_groups.h>

namespace cg = cooperative_groups;

// TrajectoryRasterizer: heat[img,h,w] = sum_o f_o(h)*g_o(w) (separable gaussian),
// then per-image max-normalize. img = b*t = 64, o = 32, h = 181, w = 360.
//
// Fused single-kernel plan (cooperative): compute 8x8 register tiles once,
// block-reduce max -> partial slot, grid.sync(), fold scale into the tile,
// write once. Staging + 133M FMAs + 16.7MB write each happen exactly once.
// Fallback (if cooperative launch fails, e.g. capture incompat): round-2
// two-pass compute-twice kernels.

#define NH 181
#define NW 360
#define NO 32
#define NIMG 64
#define NCH 6        // row chunks of 32 (covers 192 >= 181 rows)
#define CROWS 32
#define TM 8         // rows per thread
#define NTX 45       // col groups; thread covers cols [tx*4..+3] and [180+tx*4..+3]
#define TY 4         // row tiles per block (TY*TM = 32 rows)
#define NTHR 192     // 45*4 = 180 active, padded to 3 waves

#define SIGC (-0.5f / (2.5f * 2.5f + 1e-8f))

// ---------------- fused cooperative kernel ----------------

__global__ __launch_bounds__(NTHR) void traj_fused(
    const float* __restrict__ traj,   // (64, 32, 2)
    const float* __restrict__ lat,    // (181,)
    const float* __restrict__ lon,    // (360,)
    float* __restrict__ out,          // (64, 181, 360)
    float* __restrict__ maxbuf        // (64, NCH) partial maxes in d_ws
) {
    const int img = blockIdx.x;
    const int chunk = blockIdx.y;
    const int tid = threadIdx.x;

    __shared__ float fs[NO][CROWS];
    __shared__ float gs[NO][NW];
    __shared__ float red[NTHR / 64];

    // Stage separable factors (unscaled).
    for (int i = tid; i < NO * CROWS; i += NTHR) {
        const int k = i >> 5, r = i & 31;
        const int row = chunk * CROWS + r;
        float v = 0.0f;
        if (row < NH) {
            const float d = lat[row] - traj[(img * NO + k) * 2 + 0];
            v = __expf(SIGC * d * d);
        }
        fs[k][r] = v;
    }
    for (int i = tid; i < NO * NW; i += NTHR) {
        const int k = i / NW, w = i - k * NW;
        const float d = lon[w] - traj[(img * NO + k) * 2 + 1];
        gs[k][w] = __expf(SIGC * d * d);
    }
    __syncthreads();

    const int tx = tid % NTX, ty = tid / NTX;   // ty in [0,4) for active threads
    const int w0 = tx * 4;
    const int r0 = ty * TM;
    const bool active = tid < NTX * TY;

    float acc[TM][8];
    #pragma unroll
    for (int i = 0; i < TM; ++i)
        #pragma unroll
        for (int j = 0; j < 8; ++j) acc[i][j] = 0.0f;

    float lmax = 0.0f;
    if (active) {
        #pragma unroll 2
        for (int k = 0; k < NO; ++k) {
            const float4 gA = *(const float4*)&gs[k][w0];
            const float4 gB = *(const float4*)&gs[k][w0 + 180];
            const float4 fA = *(const float4*)&fs[k][r0];
            const float4 fB = *(const float4*)&fs[k][r0 + 4];
            const float fr[TM] = {fA.x, fA.y, fA.z, fA.w, fB.x, fB.y, fB.z, fB.w};
            const float gr[8]  = {gA.x, gA.y, gA.z, gA.w, gB.x, gB.y, gB.z, gB.w};
            #pragma unroll
            for (int i = 0; i < TM; ++i)
                #pragma unroll
                for (int j = 0; j < 8; ++j)
                    acc[i][j] += fr[i] * gr[j];
        }
        #pragma unroll
        for (int i = 0; i < TM; ++i) {
            if (chunk * CROWS + r0 + i < NH) {
                #pragma unroll
                for (int j = 0; j < 8; ++j) lmax = fmaxf(lmax, acc[i][j]);
            }
        }
    }

    // Block max: wave shuffle, then across 3 waves via LDS.
    #pragma unroll
    for (int off = 32; off > 0; off >>= 1)
        lmax = fmaxf(lmax, __shfl_down(lmax, off, 64));
    if ((tid & 63) == 0) red[tid >> 6] = lmax;
    __syncthreads();
    if (tid == 0) {
        const float bm = fmaxf(fmaxf(red[0], red[1]), red[2]);
        __hip_atomic_store(&maxbuf[img * NCH + chunk], bm,
                           __ATOMIC_RELEASE, __HIP_MEMORY_SCOPE_AGENT);
    }

    cg::this_grid().sync();

    float m = 0.0f;
    #pragma unroll
    for (int c = 0; c < NCH; ++c)
        m = fmaxf(m, __hip_atomic_load(&maxbuf[img * NCH + c],
                                       __ATOMIC_ACQUIRE, __HIP_MEMORY_SCOPE_AGENT));
    const float s = 1.0f / (m + 1e-8f);

    if (active) {
        float* __restrict__ op = out + (size_t)img * NH * NW;
        #pragma unroll
        for (int i = 0; i < TM; ++i) {
            const int r = chunk * CROWS + r0 + i;
            if (r < NH) {
                const float4 vA = {acc[i][0] * s, acc[i][1] * s, acc[i][2] * s, acc[i][3] * s};
                const float4 vB = {acc[i][4] * s, acc[i][5] * s, acc[i][6] * s, acc[i][7] * s};
                *(float4*)&op[r * NW + w0] = vA;
                *(float4*)&op[r * NW + w0 + 180] = vB;
            }
        }
    }
}

// ---------------- fallback: round-2 two-pass ----------------

__device__ __forceinline__ float img_scale(const float* __restrict__ maxbuf, int img) {
    float m = 0.0f;
    #pragma unroll
    for (int c = 0; c < NCH; ++c) m = fmaxf(m, maxbuf[img * NCH + c]);
    return 1.0f / (m + 1e-8f);
}

template <bool WRITE>
__global__ __launch_bounds__(NTHR) void traj_pass(
    const float* __restrict__ traj,
    const float* __restrict__ lat,
    const float* __restrict__ lon,
    float* __restrict__ out,
    float* __restrict__ maxbuf
) {
    const int img = blockIdx.x;
    const int chunk = blockIdx.y;
    const int tid = threadIdx.x;

    __shared__ float fs[NO][CROWS];
    __shared__ float gs[NO][NW];
    __shared__ float red[NTHR / 64];

    const float scale = WRITE ? img_scale(maxbuf, img) : 1.0f;

    for (int i = tid; i < NO * CROWS; i += NTHR) {
        const int k = i >> 5, r = i & 31;
        const int row = chunk * CROWS + r;
        float v = 0.0f;
        if (row < NH) {
            const float d = lat[row] - traj[(img * NO + k) * 2 + 0];
            v = __expf(SIGC * d * d);
        }
        fs[k][r] = v;
    }
    for (int i = tid; i < NO * NW; i += NTHR) {
        const int k = i / NW, w = i - k * NW;
        const float d = lon[w] - traj[(img * NO + k) * 2 + 1];
        gs[k][w] = __expf(SIGC * d * d) * scale;
    }
    __syncthreads();

    float lmax = 0.0f;
    if (tid < NTX * TY) {
        const int tx = tid % NTX, ty = tid / NTX;
        const int w0 = tx * 4;
        const int r0 = ty * TM;

        float acc[TM][8];
        #pragma unroll
        for (int i = 0; i < TM; ++i)
            #pragma unroll
            for (int j = 0; j < 8; ++j) acc[i][j] = 0.0f;

        #pragma unroll 2
        for (int k = 0; k < NO; ++k) {
            const float4 gA = *(const float4*)&gs[k][w0];
            const float4 gB = *(const float4*)&gs[k][w0 + 180];
            const float4 fA = *(const float4*)&fs[k][r0];
            const float4 fB = *(const float4*)&fs[k][r0 + 4];
            const float fr[TM] = {fA.x, fA.y, fA.z, fA.w, fB.x, fB.y, fB.z, fB.w};
            const float gr[8]  = {gA.x, gA.y, gA.z, gA.w, gB.x, gB.y, gB.z, gB.w};
            #pragma unroll
            for (int i = 0; i < TM; ++i)
                #pragma unroll
                for (int j = 0; j < 8; ++j)
                    acc[i][j] += fr[i] * gr[j];
        }

        if (WRITE) {
            float* __restrict__ op = out + (size_t)img * NH * NW;
            #pragma unroll
            for (int i = 0; i < TM; ++i) {
                const int r = chunk * CROWS + r0 + i;
                if (r < NH) {
                    const float4 vA = {acc[i][0], acc[i][1], acc[i][2], acc[i][3]};
                    const float4 vB = {acc[i][4], acc[i][5], acc[i][6], acc[i][7]};
                    *(float4*)&op[r * NW + w0] = vA;
                    *(float4*)&op[r * NW + w0 + 180] = vB;
                }
            }
        } else {
            #pragma unroll
            for (int i = 0; i < TM; ++i) {
                if (chunk * CROWS + r0 + i < NH) {
                    #pragma unroll
                    for (int j = 0; j < 8; ++j) lmax = fmaxf(lmax, acc[i][j]);
                }
            }
        }
    }

    if (!WRITE) {
        #pragma unroll
        for (int off = 32; off > 0; off >>= 1)
            lmax = fmaxf(lmax, __shfl_down(lmax, off, 64));
        if ((tid & 63) == 0) red[tid >> 6] = lmax;
        __syncthreads();
        if (tid == 0)
            maxbuf[img * NCH + chunk] = fmaxf(fmaxf(red[0], red[1]), red[2]);
    }
}

extern "C" void kernel_launch(void* const* d_in, const int* in_sizes, int n_in,
                              void* d_out, int out_size, void* d_ws, size_t ws_size,
                              hipStream_t stream) {
    const float* traj = (const float*)d_in[0];  // (4,16,32,2)
    const float* lat  = (const float*)d_in[1];  // (181,)
    const float* lon  = (const float*)d_in[2];  // (360,)
    float* out = (float*)d_out;                 // (4,16,181,360) fp32
    float* maxbuf = (float*)d_ws;               // 64*NCH floats; fully written before read

    void* args[] = { (void*)&traj, (void*)&lat, (void*)&lon, (void*)&out, (void*)&maxbuf };
    hipError_t err = hipLaunchCooperativeKernel(
        (const void*)traj_fused, dim3(NIMG, NCH), dim3(NTHR), args, 0, stream);

    if (err != hipSuccess) {
        // Fallback: two-pass compute-twice (no grid sync needed).
        dim3 grid(NIMG, NCH);
        traj_pass<false><<<grid, NTHR, 0, stream>>>(traj, lat, lon, out, maxbuf);
        traj_pass<true><<<grid, NTHR, 0, stream>>>(traj, lat, lon, out, maxbuf);
    }
}

// Round 4
// 87.950 us; speedup vs baseline: 2.0568x; 2.0568x over previous
//
#include <hip/hip_runtime.h>

// TrajectoryRasterizer: heat[img,h,w] = sum_o f_o(h)*g_o(w) (separable gaussian),
// then per-image max-normalize. img = b*t = 64, o = 32, h = 181, w = 360.
//
// Two-pass compute-twice (recompute beats re-reading 33 MB; cooperative
// grid.sync measured at ~90 us on this part in R3 -- never again):
//   pass 1 (WRITE=false): field in registers, block max -> maxbuf[img][chunk].
//   pass 2 (WRITE=true):  recompute with scale folded into g staging, write once.
//
// R4: float2 packed accumulators -> v_pk_fma_f32 (halves VALU issue);
//     no integer div in staging; unroll-4 k loop.

#define NH 181
#define NW 360
#define NO 32
#define NIMG 64
#define NCH 6        // row chunks of 32 (covers 192 >= 181 rows)
#define CROWS 32
#define TM 8         // rows per thread
#define NTX 45       // col groups; thread covers cols [tx*4..+3] and [180+tx*4..+3]
#define TY 4         // row groups (TY*TM = 32 rows)
#define NTHR 192     // 45*4 = 180 active, padded to 3 waves

#define SIGC (-0.5f / (2.5f * 2.5f + 1e-8f))

typedef float v2f __attribute__((ext_vector_type(2)));

__device__ __forceinline__ float img_scale(const float* __restrict__ maxbuf, int img) {
    float m = 0.0f;
    #pragma unroll
    for (int c = 0; c < NCH; ++c) m = fmaxf(m, maxbuf[img * NCH + c]);
    return 1.0f / (m + 1e-8f);
}

template <bool WRITE>
__global__ __launch_bounds__(NTHR) void traj_pass(
    const float* __restrict__ traj,   // (64, 32, 2)
    const float* __restrict__ lat,    // (181,)
    const float* __restrict__ lon,    // (360,)
    float* __restrict__ out,          // (64, 181, 360)
    float* __restrict__ maxbuf        // (64, NCH) partial maxes in d_ws
) {
    const int img = blockIdx.x;
    const int chunk = blockIdx.y;
    const int tid = threadIdx.x;

    __shared__ float fs[NO][CROWS];   // [k][row-in-chunk]
    __shared__ float gs[NO][NW];      // [k][w]
    __shared__ float red[NTHR / 64];

    const float scale = WRITE ? img_scale(maxbuf, img) : 1.0f;

    // Stage lat-direction gaussians for this chunk's 32 rows (shift/mask only).
    for (int i = tid; i < NO * CROWS; i += NTHR) {
        const int k = i >> 5, r = i & 31;
        const int row = chunk * CROWS + r;
        float v = 0.0f;
        if (row < NH) {
            const float d = lat[row] - traj[(img * NO + k) * 2 + 0];
            v = __expf(SIGC * d * d);
        }
        fs[k][r] = v;
    }
    // Stage lon-direction gaussians; k outer / w strided inner -> no int div.
    #pragma unroll 2
    for (int k = 0; k < NO; ++k) {
        const float lt = traj[(img * NO + k) * 2 + 1];
        for (int w = tid; w < NW; w += NTHR) {
            const float d = lon[w] - lt;
            gs[k][w] = __expf(SIGC * d * d) * scale;
        }
    }
    __syncthreads();

    float lmax = 0.0f;
    if (tid < NTX * TY) {
        const int tx = tid % NTX, ty = tid / NTX;
        const int w0 = tx * 4;        // second col quad at w0 + 180 (both 16B aligned)
        const int r0 = ty * TM;

        // Packed accumulators: acc[i][j] = cols {w0+2j, w0+2j+1} (j<2) or
        // {180+w0+2(j-2), ...} (j>=2) for row r0+i.
        v2f acc[TM][4];
        #pragma unroll
        for (int i = 0; i < TM; ++i)
            #pragma unroll
            for (int j = 0; j < 4; ++j) acc[i][j] = (v2f){0.0f, 0.0f};

        #pragma unroll 4
        for (int k = 0; k < NO; ++k) {
            const float4 gA = *(const float4*)&gs[k][w0];
            const float4 gB = *(const float4*)&gs[k][w0 + 180];
            const float4 fA = *(const float4*)&fs[k][r0];
            const float4 fB = *(const float4*)&fs[k][r0 + 4];
            const v2f g[4] = {{gA.x, gA.y}, {gA.z, gA.w}, {gB.x, gB.y}, {gB.z, gB.w}};
            const float fr[TM] = {fA.x, fA.y, fA.z, fA.w, fB.x, fB.y, fB.z, fB.w};
            #pragma unroll
            for (int i = 0; i < TM; ++i) {
                const v2f fv = {fr[i], fr[i]};
                #pragma unroll
                for (int j = 0; j < 4; ++j)
                    acc[i][j] = __builtin_elementwise_fma(fv, g[j], acc[i][j]);
            }
        }

        if (WRITE) {
            float* __restrict__ op = out + (size_t)img * NH * NW;
            #pragma unroll
            for (int i = 0; i < TM; ++i) {
                const int r = chunk * CROWS + r0 + i;
                if (r < NH) {
                    const float4 vA = {acc[i][0].x, acc[i][0].y, acc[i][1].x, acc[i][1].y};
                    const float4 vB = {acc[i][2].x, acc[i][2].y, acc[i][3].x, acc[i][3].y};
                    *(float4*)&op[r * NW + w0] = vA;
                    *(float4*)&op[r * NW + w0 + 180] = vB;
                }
            }
        } else {
            v2f vmax = {0.0f, 0.0f};
            #pragma unroll
            for (int i = 0; i < TM; ++i) {
                if (chunk * CROWS + r0 + i < NH) {
                    #pragma unroll
                    for (int j = 0; j < 4; ++j)
                        vmax = __builtin_elementwise_max(vmax, acc[i][j]);
                }
            }
            lmax = fmaxf(vmax.x, vmax.y);
        }
    }

    if (!WRITE) {
        // Block max: wave shuffle reduce, then across 3 waves via LDS.
        #pragma unroll
        for (int off = 32; off > 0; off >>= 1)
            lmax = fmaxf(lmax, __shfl_down(lmax, off, 64));
        if ((tid & 63) == 0) red[tid >> 6] = lmax;
        __syncthreads();
        if (tid == 0)
            maxbuf[img * NCH + chunk] = fmaxf(fmaxf(red[0], red[1]), red[2]);
    }
}

extern "C" void kernel_launch(void* const* d_in, const int* in_sizes, int n_in,
                              void* d_out, int out_size, void* d_ws, size_t ws_size,
                              hipStream_t stream) {
    const float* traj = (const float*)d_in[0];  // (4,16,32,2)
    const float* lat  = (const float*)d_in[1];  // (181,)
    const float* lon  = (const float*)d_in[2];  // (360,)
    float* out = (float*)d_out;                 // (4,16,181,360) fp32
    float* maxbuf = (float*)d_ws;               // 64*NCH floats; fully written by pass 1

    dim3 grid(NIMG, NCH);
    traj_pass<false><<<grid, NTHR, 0, stream>>>(traj, lat, lon, out, maxbuf);
    traj_pass<true><<<grid, NTHR, 0, stream>>>(traj, lat, lon, out, maxbuf);
}